// Round 8
// baseline (475.753 us; speedup 1.0000x reference)
//
#include <hip/hip_runtime.h>
#include <math.h>

// Location-aware attention (ESPnet AttLoc), T=50000, ATT=EPROJ=512, DUNITS=1024,
// CH=10, KW=201, FILTS=100, SCALING=2.
//
// FLASH-STYLE SINGLE BIG PASS (R7 post-mortem: each big-array pass costs ~60 µs
// regardless of tuning -> eliminate one pass entirely):
// K0: conv1d(att_prev) -> ws_aconv[T][12]; dec_z@w_dec.T -> ws_dec.
// K1: per t: y = 2*(gvec.tanh(pre+dec+aconv@w_att^T)+b+mask) -> ws_e;
//     ONLINE softmax (m,s) AND online context c += exp(y-m)*enc_h[t] with
//     rescaling (flash-attention recurrence). Per-block partials:
//     ws_ms[b]=(m,s), ws_c[b][512]. No second 102MB pass, no atomics.
// K2: merge 1024 (m,s) -> (M,1/S); c = IS*sum_b exp(m_b-M)*ws_c[b][:] -> out[0:512);
//     w[t] = exp(ws_e[t]-M)*IS -> out[512+t).

constexpr int ATT    = 512;
constexpr int CH     = 10;
constexpr int PCH    = 12;     // padded channel stride (48 B, float4-aligned)
constexpr int KW     = 201;
constexpr int FILTS  = 100;
constexpr int DUNITS = 1024;
constexpr int NB1    = 1024;   // K1 grid (fixed: K2 merges exactly NB1 partials)
constexpr int CT     = 64;     // t-tile per conv block
constexpr float SCALING = 2.0f;

__device__ __forceinline__ float wave_reduce_sum(float v) {
    #pragma unroll
    for (int off = 32; off > 0; off >>= 1) v += __shfl_xor(v, off, 64);
    return v;
}

// tanh(x) = 1 - 2/(e^{2x}+1): clamp-free, NaN-safe (e=inf -> 1, e=0 -> -1)
__device__ __forceinline__ float fast_tanh(float x) {
    float e = __expf(2.f * x);
    return 1.f - __fdividef(2.f, e + 1.f);
}

// ---------------- K0: conv over att_prev + dec projection ----------------
__global__ __launch_bounds__(256, 4) void k0_conv_dec(
    const float* __restrict__ att_prev,
    const float* __restrict__ conv_w,   // [CH][1][KW]
    const float* __restrict__ dec_z,    // [DUNITS]
    const float* __restrict__ w_dec,    // [ATT][DUNITS]
    float* __restrict__ ws_aconv,       // [T][PCH]
    float* __restrict__ ws_dec,         // [ATT]
    int T, int nbconv)
{
    if ((int)blockIdx.x < nbconv) {
        __shared__ float s_ap[CT + KW - 1];     // 264
        __shared__ float s_wt[KW * 12];         // transposed weights [k][c], pad 12
        __shared__ float s_part[4 * CT * CH];   // per-wave partials
        const int t0 = blockIdx.x * CT;
        for (int i = threadIdx.x; i < CT + KW - 1; i += 256) {
            int t = t0 - FILTS + i;
            s_ap[i] = (t >= 0 && t < T) ? att_prev[t] : 0.f;
        }
        for (int i = threadIdx.x; i < CH * KW; i += 256) {
            int c = i % CH, k = i / CH;
            s_wt[k * 12 + c] = conv_w[c * KW + k];
        }
        __syncthreads();
        const int tl = threadIdx.x & 63;   // t within tile
        const int kq = threadIdx.x >> 6;   // tap quarter (wave id)
        float acc[CH];
        #pragma unroll
        for (int c = 0; c < CH; ++c) acc[c] = 0.f;
        for (int k = kq; k < KW; k += 4) {
            float x = s_ap[tl + k];
            const float4 w0 = *(const float4*)&s_wt[k * 12];
            const float4 w1 = *(const float4*)&s_wt[k * 12 + 4];
            const float2 w2 = *(const float2*)&s_wt[k * 12 + 8];
            acc[0] += x * w0.x; acc[1] += x * w0.y;
            acc[2] += x * w0.z; acc[3] += x * w0.w;
            acc[4] += x * w1.x; acc[5] += x * w1.y;
            acc[6] += x * w1.z; acc[7] += x * w1.w;
            acc[8] += x * w2.x; acc[9] += x * w2.y;
        }
        #pragma unroll
        for (int c = 0; c < CH; ++c) s_part[kq * (CT * CH) + tl * CH + c] = acc[c];
        __syncthreads();
        for (int idx = threadIdx.x; idx < CT * PCH; idx += 256) {
            int t = idx / PCH, c = idx % PCH;
            float v = 0.f;
            if (c < CH) {
                int j = t * CH + c;
                v = s_part[j] + s_part[CT * CH + j]
                  + s_part[2 * CT * CH + j] + s_part[3 * CT * CH + j];
            }
            if (t0 + t < T) ws_aconv[(size_t)(t0 + t) * PCH + c] = v;
        }
    } else {
        const int b    = blockIdx.x - nbconv;          // 0..127
        const int wid  = threadIdx.x >> 6;
        const int lane = threadIdx.x & 63;
        const int a    = b * 4 + wid;                  // 0..511
        const float4* wd = (const float4*)(w_dec + (size_t)a * DUNITS);
        const float4* dz = (const float4*)dec_z;
        float acc = 0.f;
        #pragma unroll
        for (int q = 0; q < 4; ++q) {
            float4 wv = wd[lane + q * 64];
            float4 zv = dz[lane + q * 64];
            acc += wv.x * zv.x + wv.y * zv.y + wv.z * zv.z + wv.w * zv.w;
        }
        acc = wave_reduce_sum(acc);
        if (lane == 0) ws_dec[a] = acc;
    }
}

// ---------------- K1: scores + online softmax + online context ----------------
__global__ __launch_bounds__(256, 3) void k1_scores(
    const float* __restrict__ pre,       // [T][512]
    const float* __restrict__ enc_h,     // [T][512]
    const float* __restrict__ mask,      // [T]
    const float* __restrict__ w_att,     // [512][10]
    const float* __restrict__ w_gvec,    // [512]
    const float* __restrict__ b_gvec,    // [1]
    const float* __restrict__ ws_dec,    // [512]
    const float* __restrict__ ws_aconv,  // [T][PCH]
    float* __restrict__ ws_e,            // [T]
    float* __restrict__ ws_ms,           // [NB1*2]
    float* __restrict__ ws_c,            // [NB1][512]
    int T)
{
    const int wid  = threadIdx.x >> 6;
    const int lane = threadIdx.x & 63;

    // lane owns a-dims: j<4 -> lane*4+j ; j>=4 -> 256+lane*4+(j-4) (registers)
    float wa[8][CH];
    #pragma unroll
    for (int j = 0; j < 4; ++j) {
        #pragma unroll
        for (int c = 0; c < CH; ++c) {
            wa[j][c]     = w_att[(lane * 4 + j) * CH + c];
            wa[4 + j][c] = w_att[(256 + lane * 4 + j) * CH + c];
        }
    }
    const float4 dlo = ((const float4*)ws_dec)[lane];
    const float4 dhi = ((const float4*)ws_dec)[64 + lane];
    const float4 glo = ((const float4*)w_gvec)[lane];
    const float4 ghi = ((const float4*)w_gvec)[64 + lane];
    const float  bg  = b_gvec[0];

    const float4* pre4 = (const float4*)pre;
    const float4* eh4  = (const float4*)enc_h;
    const float4* ac4  = (const float4*)ws_aconv;   // 3 float4 per t
    const int gw = blockIdx.x * 4 + wid;
    const int t0 = gw * 4;
    constexpr int S = NB1 * 16;                     // 16384; 4 batches cover T

    float m = -INFINITY, s = 0.f;
    float4 cA0 = make_float4(0.f, 0.f, 0.f, 0.f);   // online context, lane dims lo
    float4 cA1 = make_float4(0.f, 0.f, 0.f, 0.f);   // online context, lane dims hi
    float4 pA0[4], pA1[4], pB0[4], pB1[4];
    float  mA[4], mB[4];
    float4 acx[4], acy[4], acz[4];                  // aconv[t][0..11], uniform

    auto loadp = [&](float4 (&P0)[4], float4 (&P1)[4], float (&MSK)[4], int tb) {
        #pragma unroll
        for (int i = 0; i < 4; ++i) {
            int t = tb + i;
            if (t < T) {
                P0[i]  = pre4[(size_t)t * 128 + lane];
                P1[i]  = pre4[(size_t)t * 128 + 64 + lane];
                MSK[i] = mask[t];
            }
        }
    };
    auto loada = [&](int tb) {
        #pragma unroll
        for (int i = 0; i < 4; ++i) {
            int t = tb + i;
            if (t < T) {
                acx[i] = ac4[(size_t)t * 3 + 0];
                acy[i] = ac4[(size_t)t * 3 + 1];
                acz[i] = ac4[(size_t)t * 3 + 2];
            }
        }
    };
    auto batch = [&](float4 (&P0)[4], float4 (&P1)[4], float (&MSK)[4], int tb,
                     float4 (&NP0)[4], float4 (&NP1)[4], float (&NM)[4], int tn,
                     bool pf) {
        if (pf) loadp(NP0, NP1, NM, tn);   // next pre batch in flight over compute
        // enc_h loads for THIS batch: issued now, consumed after AV/tanh/reduce
        // (~1000 cyc of compute covers their latency). Zero-init: OOB lanes must
        // contribute exactly 0 (0 * uninit could be NaN).
        float4 E0[4], E1[4];
        const float4 z4 = make_float4(0.f, 0.f, 0.f, 0.f);
        #pragma unroll
        for (int i = 0; i < 4; ++i) {
            int t = tb + i;
            E0[i] = z4; E1[i] = z4;
            if (t < T) {
                E0[i] = eh4[(size_t)t * 128 + lane];
                E1[i] = eh4[(size_t)t * 128 + 64 + lane];
            }
        }
        float y[4];
        #pragma unroll
        for (int i = 0; i < 4; ++i) {
            const int t = tb + i;
            y[i] = -INFINITY;
            if (t < T) {
                const float4 a0 = acx[i], a1 = acy[i], a2 = acz[i];
                float x0 = P0[i].x + dlo.x, x1 = P0[i].y + dlo.y;
                float x2 = P0[i].z + dlo.z, x3 = P0[i].w + dlo.w;
                float x4 = P1[i].x + dhi.x, x5 = P1[i].y + dhi.y;
                float x6 = P1[i].z + dhi.z, x7 = P1[i].w + dhi.w;
                #define AV(X, J) \
                    X += a0.x*wa[J][0] + a0.y*wa[J][1] + a0.z*wa[J][2] + a0.w*wa[J][3] \
                       + a1.x*wa[J][4] + a1.y*wa[J][5] + a1.z*wa[J][6] + a1.w*wa[J][7] \
                       + a2.x*wa[J][8] + a2.y*wa[J][9]
                AV(x0, 0); AV(x1, 1); AV(x2, 2); AV(x3, 3);
                AV(x4, 4); AV(x5, 5); AV(x6, 6); AV(x7, 7);
                #undef AV
                float acc = glo.x * fast_tanh(x0) + glo.y * fast_tanh(x1)
                          + glo.z * fast_tanh(x2) + glo.w * fast_tanh(x3)
                          + ghi.x * fast_tanh(x4) + ghi.y * fast_tanh(x5)
                          + ghi.z * fast_tanh(x6) + ghi.w * fast_tanh(x7);
                acc = wave_reduce_sum(acc);
                float yy = SCALING * (acc + bg + MSK[i]);
                if (lane == 0) ws_e[t] = yy;
                y[i] = yy;
            }
        }
        if (pf) loada(tn);                 // aconv regs dead now; reload for next
        // flash recurrence: batched (4 exps + 1 rescale per batch)
        float ymax = fmaxf(fmaxf(y[0], y[1]), fmaxf(y[2], y[3]));
        float nm = fmaxf(m, ymax);          // finite: batch 0 always has valid t
        float sc = __expf(m - nm);          // m=-inf first batch -> sc=0, c=0 ok
        float w0 = __expf(y[0] - nm), w1 = __expf(y[1] - nm);
        float w2 = __expf(y[2] - nm), w3 = __expf(y[3] - nm);
        s = s * sc + (w0 + w1 + w2 + w3);
        cA0.x = cA0.x * sc + w0*E0[0].x + w1*E0[1].x + w2*E0[2].x + w3*E0[3].x;
        cA0.y = cA0.y * sc + w0*E0[0].y + w1*E0[1].y + w2*E0[2].y + w3*E0[3].y;
        cA0.z = cA0.z * sc + w0*E0[0].z + w1*E0[1].z + w2*E0[2].z + w3*E0[3].z;
        cA0.w = cA0.w * sc + w0*E0[0].w + w1*E0[1].w + w2*E0[2].w + w3*E0[3].w;
        cA1.x = cA1.x * sc + w0*E1[0].x + w1*E1[1].x + w2*E1[2].x + w3*E1[3].x;
        cA1.y = cA1.y * sc + w0*E1[0].y + w1*E1[1].y + w2*E1[2].y + w3*E1[3].y;
        cA1.z = cA1.z * sc + w0*E1[0].z + w1*E1[1].z + w2*E1[2].z + w3*E1[3].z;
        cA1.w = cA1.w * sc + w0*E1[0].w + w1*E1[1].w + w2*E1[2].w + w3*E1[3].w;
        m = nm;
    };

    loadp(pA0, pA1, mA, t0);
    loada(t0);
    batch(pA0, pA1, mA, t0,         pB0, pB1, mB, t0 + S,     true);
    batch(pB0, pB1, mB, t0 + S,     pA0, pA1, mA, t0 + 2 * S, true);
    batch(pA0, pA1, mA, t0 + 2 * S, pB0, pB1, mB, t0 + 3 * S, true);
    batch(pB0, pB1, mB, t0 + 3 * S, pA0, pA1, mA, 0,          false);

    // ---- fold 4 waves' (m, s, c) into block partial ----
    __shared__ float4 s_c[4 * 128];   // [wave][512 floats]
    __shared__ float  s_mw[4], s_sw[4];
    s_c[wid * 128 + lane]      = cA0;
    s_c[wid * 128 + 64 + lane] = cA1;
    if (lane == 0) { s_mw[wid] = m; s_sw[wid] = s; }
    __syncthreads();
    const float mb = fmaxf(fmaxf(s_mw[0], s_mw[1]), fmaxf(s_mw[2], s_mw[3]));
    const float sc0 = __expf(s_mw[0] - mb), sc1 = __expf(s_mw[1] - mb);
    const float sc2 = __expf(s_mw[2] - mb), sc3 = __expf(s_mw[3] - mb);
    const float* scf = (const float*)s_c;
    for (int a = threadIdx.x; a < ATT; a += 256) {
        float v = sc0 * scf[a] + sc1 * scf[512 + a]
                + sc2 * scf[1024 + a] + sc3 * scf[1536 + a];
        ws_c[(size_t)blockIdx.x * ATT + a] = v;
    }
    if (threadIdx.x == 0) {
        ws_ms[blockIdx.x * 2]     = mb;
        ws_ms[blockIdx.x * 2 + 1] = sc0 * s_sw[0] + sc1 * s_sw[1]
                                  + sc2 * s_sw[2] + sc3 * s_sw[3];
    }
}

// ---------------- K2: merge partials; write c and w ----------------
__global__ __launch_bounds__(256, 4) void k2_final(
    const float* __restrict__ ws_e,      // [T]
    const float* __restrict__ ws_ms,     // [NB1*2]
    const float* __restrict__ ws_c,      // [NB1][512]
    float* __restrict__ out,             // [0:512)=c, [512:512+T)=w
    int T)
{
    __shared__ float s_m[256], s_s[256];
    // Phase A: every block merges the NB1 (m,s) partials -> (M, 1/S)
    {
        float m = -INFINITY, s = 0.f;
        for (int i = threadIdx.x; i < NB1; i += 256) {
            float m2 = ws_ms[i * 2], s2 = ws_ms[i * 2 + 1];
            float nm = fmaxf(m, m2);
            s = s * __expf(m - nm) + s2 * __expf(m2 - nm);
            m = nm;
        }
        s_m[threadIdx.x] = m; s_s[threadIdx.x] = s;
        __syncthreads();
        for (int off = 128; off > 0; off >>= 1) {
            if ((int)threadIdx.x < off) {
                float M1 = s_m[threadIdx.x], S1 = s_s[threadIdx.x];
                float m2 = s_m[threadIdx.x + off], s2 = s_s[threadIdx.x + off];
                float nm = fmaxf(M1, m2);
                s_s[threadIdx.x] = S1 * __expf(M1 - nm) + s2 * __expf(m2 - nm);
                s_m[threadIdx.x] = nm;
            }
            __syncthreads();
        }
    }
    const float M  = s_m[0];
    const float IS = 1.f / s_s[0];

    // Phase B: blocks 0..31 merge context partials -> out[0:512)
    if (blockIdx.x < 32) {
        __shared__ float s_scale[NB1];    // 4 KiB
        for (int b = threadIdx.x; b < NB1; b += 256)
            s_scale[b] = __expf(ws_ms[b * 2] - M);
        __syncthreads();
        const int al = threadIdx.x >> 4;          // 0..15 -> dim within block
        const int ch = threadIdx.x & 15;          // 0..15 -> b-chunk
        const int a  = blockIdx.x * 16 + al;
        float acc = 0.f;
        for (int b = ch * (NB1 / 16); b < (ch + 1) * (NB1 / 16); ++b)
            acc += s_scale[b] * ws_c[(size_t)b * ATT + a];
        __shared__ float s_p[256];
        s_p[threadIdx.x] = acc;
        __syncthreads();
        if (ch == 0) {
            float v = 0.f;
            #pragma unroll
            for (int k = 0; k < 16; ++k) v += s_p[al * 16 + k];
            out[a] = v * IS;
        }
    }

    // Phase C: attention weights w[t] -> out[512+t)
    const int t = blockIdx.x * 256 + threadIdx.x;
    if (t < T) out[ATT + t] = __expf(ws_e[t] - M) * IS;
}

extern "C" void kernel_launch(void* const* d_in, const int* in_sizes, int n_in,
                              void* d_out, int out_size, void* d_ws, size_t ws_size,
                              hipStream_t stream)
{
    const float* dec_z    = (const float*)d_in[0];
    const float* att_prev = (const float*)d_in[1];
    const float* pre      = (const float*)d_in[2];
    const float* enc_h    = (const float*)d_in[3];
    const float* mask     = (const float*)d_in[4];
    const float* conv_w   = (const float*)d_in[5];
    const float* w_att    = (const float*)d_in[6];
    const float* w_dec    = (const float*)d_in[7];
    const float* w_gvec   = (const float*)d_in[8];
    const float* b_gvec   = (const float*)d_in[9];
    const int T = in_sizes[1];

    float* ws       = (float*)d_ws;
    float* ws_dec   = ws;                          // 512
    float* ws_aconv = ws_dec + ATT;                // T*PCH (16B-aligned)
    float* ws_e     = ws_aconv + (size_t)T * PCH;  // T
    float* ws_ms    = ws_e + T;                    // NB1*2
    float* ws_c     = ws_ms + NB1 * 2;             // NB1*512
    float* out      = (float*)d_out;

    const int nbconv = (T + CT - 1) / CT;
    const int nb2    = (T + 255) / 256;            // 196 >= 32 blocks for Phase B

    hipLaunchKernelGGL(k0_conv_dec, dim3(nbconv + ATT / 4), dim3(256), 0, stream,
                       att_prev, conv_w, dec_z, w_dec, ws_aconv, ws_dec, T, nbconv);
    hipLaunchKernelGGL(k1_scores, dim3(NB1), dim3(256), 0, stream,
                       pre, enc_h, mask, w_att, w_gvec, b_gvec, ws_dec, ws_aconv,
                       ws_e, ws_ms, ws_c, T);
    hipLaunchKernelGGL(k2_final, dim3(nb2), dim3(256), 0, stream,
                       ws_e, ws_ms, ws_c, out, T);
}

// Round 9
// 351.489 us; speedup vs baseline: 1.3535x; 1.3535x over previous
//
#include <hip/hip_runtime.h>
#include <math.h>

// Location-aware attention (ESPnet AttLoc), T=50000, ATT=EPROJ=512, DUNITS=1024,
// CH=10, KW=201, FILTS=100, SCALING=2.
//
// FLASH-STYLE SINGLE BIG PASS. R8 post-mortem: structure correct (absmax 6e-8)
// but __launch_bounds__(256,3) capped VGPR at 84 -> ~410MB scratch spill traffic
// -> 291µs. THIS ROUND: k1 at (256,2) (R7-proven: 120 VGPR, zero spill) so the
// ~165-reg live state fits. Everything else byte-identical to the passed R8.
//
// K0: conv1d(att_prev) -> ws_aconv[T][12]; dec_z@w_dec.T -> ws_dec.
// K1: y=2*(gvec.tanh(pre+dec+aconv@w_att^T)+b+mask) -> ws_e; ONLINE (m,s) and
//     ONLINE context c += exp(y-m)*enc_h[t] (flash recurrence); block partials.
// K2: merge (m,s) -> (M,1/S); c -> out[0:512); w[t] -> out[512+t).

constexpr int ATT    = 512;
constexpr int CH     = 10;
constexpr int PCH    = 12;     // padded channel stride (48 B, float4-aligned)
constexpr int KW     = 201;
constexpr int FILTS  = 100;
constexpr int DUNITS = 1024;
constexpr int NB1    = 1024;   // K1 grid (fixed: K2 merges exactly NB1 partials)
constexpr int CT     = 64;     // t-tile per conv block
constexpr float SCALING = 2.0f;

__device__ __forceinline__ float wave_reduce_sum(float v) {
    #pragma unroll
    for (int off = 32; off > 0; off >>= 1) v += __shfl_xor(v, off, 64);
    return v;
}

// tanh(x) = 1 - 2/(e^{2x}+1): clamp-free, NaN-safe (e=inf -> 1, e=0 -> -1)
__device__ __forceinline__ float fast_tanh(float x) {
    float e = __expf(2.f * x);
    return 1.f - __fdividef(2.f, e + 1.f);
}

// ---------------- K0: conv over att_prev + dec projection ----------------
__global__ __launch_bounds__(256, 4) void k0_conv_dec(
    const float* __restrict__ att_prev,
    const float* __restrict__ conv_w,   // [CH][1][KW]
    const float* __restrict__ dec_z,    // [DUNITS]
    const float* __restrict__ w_dec,    // [ATT][DUNITS]
    float* __restrict__ ws_aconv,       // [T][PCH]
    float* __restrict__ ws_dec,         // [ATT]
    int T, int nbconv)
{
    if ((int)blockIdx.x < nbconv) {
        __shared__ float s_ap[CT + KW - 1];     // 264
        __shared__ float s_wt[KW * 12];         // transposed weights [k][c], pad 12
        __shared__ float s_part[4 * CT * CH];   // per-wave partials
        const int t0 = blockIdx.x * CT;
        for (int i = threadIdx.x; i < CT + KW - 1; i += 256) {
            int t = t0 - FILTS + i;
            s_ap[i] = (t >= 0 && t < T) ? att_prev[t] : 0.f;
        }
        for (int i = threadIdx.x; i < CH * KW; i += 256) {
            int c = i % CH, k = i / CH;
            s_wt[k * 12 + c] = conv_w[c * KW + k];
        }
        __syncthreads();
        const int tl = threadIdx.x & 63;   // t within tile
        const int kq = threadIdx.x >> 6;   // tap quarter (wave id)
        float acc[CH];
        #pragma unroll
        for (int c = 0; c < CH; ++c) acc[c] = 0.f;
        for (int k = kq; k < KW; k += 4) {
            float x = s_ap[tl + k];
            const float4 w0 = *(const float4*)&s_wt[k * 12];
            const float4 w1 = *(const float4*)&s_wt[k * 12 + 4];
            const float2 w2 = *(const float2*)&s_wt[k * 12 + 8];
            acc[0] += x * w0.x; acc[1] += x * w0.y;
            acc[2] += x * w0.z; acc[3] += x * w0.w;
            acc[4] += x * w1.x; acc[5] += x * w1.y;
            acc[6] += x * w1.z; acc[7] += x * w1.w;
            acc[8] += x * w2.x; acc[9] += x * w2.y;
        }
        #pragma unroll
        for (int c = 0; c < CH; ++c) s_part[kq * (CT * CH) + tl * CH + c] = acc[c];
        __syncthreads();
        for (int idx = threadIdx.x; idx < CT * PCH; idx += 256) {
            int t = idx / PCH, c = idx % PCH;
            float v = 0.f;
            if (c < CH) {
                int j = t * CH + c;
                v = s_part[j] + s_part[CT * CH + j]
                  + s_part[2 * CT * CH + j] + s_part[3 * CT * CH + j];
            }
            if (t0 + t < T) ws_aconv[(size_t)(t0 + t) * PCH + c] = v;
        }
    } else {
        const int b    = blockIdx.x - nbconv;          // 0..127
        const int wid  = threadIdx.x >> 6;
        const int lane = threadIdx.x & 63;
        const int a    = b * 4 + wid;                  // 0..511
        const float4* wd = (const float4*)(w_dec + (size_t)a * DUNITS);
        const float4* dz = (const float4*)dec_z;
        float acc = 0.f;
        #pragma unroll
        for (int q = 0; q < 4; ++q) {
            float4 wv = wd[lane + q * 64];
            float4 zv = dz[lane + q * 64];
            acc += wv.x * zv.x + wv.y * zv.y + wv.z * zv.z + wv.w * zv.w;
        }
        acc = wave_reduce_sum(acc);
        if (lane == 0) ws_dec[a] = acc;
    }
}

// ---------------- K1: scores + online softmax + online context ----------------
__global__ __launch_bounds__(256, 2) void k1_scores(
    const float* __restrict__ pre,       // [T][512]
    const float* __restrict__ enc_h,     // [T][512]
    const float* __restrict__ mask,      // [T]
    const float* __restrict__ w_att,     // [512][10]
    const float* __restrict__ w_gvec,    // [512]
    const float* __restrict__ b_gvec,    // [1]
    const float* __restrict__ ws_dec,    // [512]
    const float* __restrict__ ws_aconv,  // [T][PCH]
    float* __restrict__ ws_e,            // [T]
    float* __restrict__ ws_ms,           // [NB1*2]
    float* __restrict__ ws_c,            // [NB1][512]
    int T)
{
    const int wid  = threadIdx.x >> 6;
    const int lane = threadIdx.x & 63;

    // lane owns a-dims: j<4 -> lane*4+j ; j>=4 -> 256+lane*4+(j-4) (registers)
    float wa[8][CH];
    #pragma unroll
    for (int j = 0; j < 4; ++j) {
        #pragma unroll
        for (int c = 0; c < CH; ++c) {
            wa[j][c]     = w_att[(lane * 4 + j) * CH + c];
            wa[4 + j][c] = w_att[(256 + lane * 4 + j) * CH + c];
        }
    }
    const float4 dlo = ((const float4*)ws_dec)[lane];
    const float4 dhi = ((const float4*)ws_dec)[64 + lane];
    const float4 glo = ((const float4*)w_gvec)[lane];
    const float4 ghi = ((const float4*)w_gvec)[64 + lane];
    const float  bg  = b_gvec[0];

    const float4* pre4 = (const float4*)pre;
    const float4* eh4  = (const float4*)enc_h;
    const float4* ac4  = (const float4*)ws_aconv;   // 3 float4 per t
    const int gw = blockIdx.x * 4 + wid;
    const int t0 = gw * 4;
    constexpr int S = NB1 * 16;                     // 16384; 4 batches cover T

    float m = -INFINITY, s = 0.f;
    float4 cA0 = make_float4(0.f, 0.f, 0.f, 0.f);   // online context, lane dims lo
    float4 cA1 = make_float4(0.f, 0.f, 0.f, 0.f);   // online context, lane dims hi
    float4 pA0[4], pA1[4], pB0[4], pB1[4];
    float  mA[4], mB[4];
    float4 acx[4], acy[4], acz[4];                  // aconv[t][0..11], uniform

    auto loadp = [&](float4 (&P0)[4], float4 (&P1)[4], float (&MSK)[4], int tb) {
        #pragma unroll
        for (int i = 0; i < 4; ++i) {
            int t = tb + i;
            if (t < T) {
                P0[i]  = pre4[(size_t)t * 128 + lane];
                P1[i]  = pre4[(size_t)t * 128 + 64 + lane];
                MSK[i] = mask[t];
            }
        }
    };
    auto loada = [&](int tb) {
        #pragma unroll
        for (int i = 0; i < 4; ++i) {
            int t = tb + i;
            if (t < T) {
                acx[i] = ac4[(size_t)t * 3 + 0];
                acy[i] = ac4[(size_t)t * 3 + 1];
                acz[i] = ac4[(size_t)t * 3 + 2];
            }
        }
    };
    auto batch = [&](float4 (&P0)[4], float4 (&P1)[4], float (&MSK)[4], int tb,
                     float4 (&NP0)[4], float4 (&NP1)[4], float (&NM)[4], int tn,
                     bool pf) {
        if (pf) loadp(NP0, NP1, NM, tn);   // next pre batch in flight over compute
        // enc_h loads for THIS batch: issued now, consumed after AV/tanh/reduce.
        // Zero-init: OOB lanes must contribute exactly 0.
        float4 E0[4], E1[4];
        const float4 z4 = make_float4(0.f, 0.f, 0.f, 0.f);
        #pragma unroll
        for (int i = 0; i < 4; ++i) {
            int t = tb + i;
            E0[i] = z4; E1[i] = z4;
            if (t < T) {
                E0[i] = eh4[(size_t)t * 128 + lane];
                E1[i] = eh4[(size_t)t * 128 + 64 + lane];
            }
        }
        float y[4];
        #pragma unroll
        for (int i = 0; i < 4; ++i) {
            const int t = tb + i;
            y[i] = -INFINITY;
            if (t < T) {
                const float4 a0 = acx[i], a1 = acy[i], a2 = acz[i];
                float x0 = P0[i].x + dlo.x, x1 = P0[i].y + dlo.y;
                float x2 = P0[i].z + dlo.z, x3 = P0[i].w + dlo.w;
                float x4 = P1[i].x + dhi.x, x5 = P1[i].y + dhi.y;
                float x6 = P1[i].z + dhi.z, x7 = P1[i].w + dhi.w;
                #define AV(X, J) \
                    X += a0.x*wa[J][0] + a0.y*wa[J][1] + a0.z*wa[J][2] + a0.w*wa[J][3] \
                       + a1.x*wa[J][4] + a1.y*wa[J][5] + a1.z*wa[J][6] + a1.w*wa[J][7] \
                       + a2.x*wa[J][8] + a2.y*wa[J][9]
                AV(x0, 0); AV(x1, 1); AV(x2, 2); AV(x3, 3);
                AV(x4, 4); AV(x5, 5); AV(x6, 6); AV(x7, 7);
                #undef AV
                float acc = glo.x * fast_tanh(x0) + glo.y * fast_tanh(x1)
                          + glo.z * fast_tanh(x2) + glo.w * fast_tanh(x3)
                          + ghi.x * fast_tanh(x4) + ghi.y * fast_tanh(x5)
                          + ghi.z * fast_tanh(x6) + ghi.w * fast_tanh(x7);
                acc = wave_reduce_sum(acc);
                float yy = SCALING * (acc + bg + MSK[i]);
                if (lane == 0) ws_e[t] = yy;
                y[i] = yy;
            }
        }
        if (pf) loada(tn);                 // aconv regs dead now; reload for next
        // flash recurrence: batched (4 exps + 1 rescale per batch)
        float ymax = fmaxf(fmaxf(y[0], y[1]), fmaxf(y[2], y[3]));
        float nm = fmaxf(m, ymax);          // finite: batch 0 always has valid t
        float sc = __expf(m - nm);          // m=-inf first batch -> sc=0, c=0 ok
        float w0 = __expf(y[0] - nm), w1 = __expf(y[1] - nm);
        float w2 = __expf(y[2] - nm), w3 = __expf(y[3] - nm);
        s = s * sc + (w0 + w1 + w2 + w3);
        cA0.x = cA0.x * sc + w0*E0[0].x + w1*E0[1].x + w2*E0[2].x + w3*E0[3].x;
        cA0.y = cA0.y * sc + w0*E0[0].y + w1*E0[1].y + w2*E0[2].y + w3*E0[3].y;
        cA0.z = cA0.z * sc + w0*E0[0].z + w1*E0[1].z + w2*E0[2].z + w3*E0[3].z;
        cA0.w = cA0.w * sc + w0*E0[0].w + w1*E0[1].w + w2*E0[2].w + w3*E0[3].w;
        cA1.x = cA1.x * sc + w0*E1[0].x + w1*E1[1].x + w2*E1[2].x + w3*E1[3].x;
        cA1.y = cA1.y * sc + w0*E1[0].y + w1*E1[1].y + w2*E1[2].y + w3*E1[3].y;
        cA1.z = cA1.z * sc + w0*E1[0].z + w1*E1[1].z + w2*E1[2].z + w3*E1[3].z;
        cA1.w = cA1.w * sc + w0*E1[0].w + w1*E1[1].w + w2*E1[2].w + w3*E1[3].w;
        m = nm;
    };

    loadp(pA0, pA1, mA, t0);
    loada(t0);
    batch(pA0, pA1, mA, t0,         pB0, pB1, mB, t0 + S,     true);
    batch(pB0, pB1, mB, t0 + S,     pA0, pA1, mA, t0 + 2 * S, true);
    batch(pA0, pA1, mA, t0 + 2 * S, pB0, pB1, mB, t0 + 3 * S, true);
    batch(pB0, pB1, mB, t0 + 3 * S, pA0, pA1, mA, 0,          false);

    // ---- fold 4 waves' (m, s, c) into block partial ----
    __shared__ float4 s_c[4 * 128];   // [wave][512 floats]
    __shared__ float  s_mw[4], s_sw[4];
    s_c[wid * 128 + lane]      = cA0;
    s_c[wid * 128 + 64 + lane] = cA1;
    if (lane == 0) { s_mw[wid] = m; s_sw[wid] = s; }
    __syncthreads();
    const float mb = fmaxf(fmaxf(s_mw[0], s_mw[1]), fmaxf(s_mw[2], s_mw[3]));
    const float sc0 = __expf(s_mw[0] - mb), sc1 = __expf(s_mw[1] - mb);
    const float sc2 = __expf(s_mw[2] - mb), sc3 = __expf(s_mw[3] - mb);
    const float* scf = (const float*)s_c;
    for (int a = threadIdx.x; a < ATT; a += 256) {
        float v = sc0 * scf[a] + sc1 * scf[512 + a]
                + sc2 * scf[1024 + a] + sc3 * scf[1536 + a];
        ws_c[(size_t)blockIdx.x * ATT + a] = v;
    }
    if (threadIdx.x == 0) {
        ws_ms[blockIdx.x * 2]     = mb;
        ws_ms[blockIdx.x * 2 + 1] = sc0 * s_sw[0] + sc1 * s_sw[1]
                                  + sc2 * s_sw[2] + sc3 * s_sw[3];
    }
}

// ---------------- K2: merge partials; write c and w ----------------
__global__ __launch_bounds__(256, 4) void k2_final(
    const float* __restrict__ ws_e,      // [T]
    const float* __restrict__ ws_ms,     // [NB1*2]
    const float* __restrict__ ws_c,      // [NB1][512]
    float* __restrict__ out,             // [0:512)=c, [512:512+T)=w
    int T)
{
    __shared__ float s_m[256], s_s[256];
    // Phase A: every block merges the NB1 (m,s) partials -> (M, 1/S)
    {
        float m = -INFINITY, s = 0.f;
        for (int i = threadIdx.x; i < NB1; i += 256) {
            float m2 = ws_ms[i * 2], s2 = ws_ms[i * 2 + 1];
            float nm = fmaxf(m, m2);
            s = s * __expf(m - nm) + s2 * __expf(m2 - nm);
            m = nm;
        }
        s_m[threadIdx.x] = m; s_s[threadIdx.x] = s;
        __syncthreads();
        for (int off = 128; off > 0; off >>= 1) {
            if ((int)threadIdx.x < off) {
                float M1 = s_m[threadIdx.x], S1 = s_s[threadIdx.x];
                float m2 = s_m[threadIdx.x + off], s2 = s_s[threadIdx.x + off];
                float nm = fmaxf(M1, m2);
                s_s[threadIdx.x] = S1 * __expf(M1 - nm) + s2 * __expf(m2 - nm);
                s_m[threadIdx.x] = nm;
            }
            __syncthreads();
        }
    }
    const float M  = s_m[0];
    const float IS = 1.f / s_s[0];

    // Phase B: blocks 0..31 merge context partials -> out[0:512)
    if (blockIdx.x < 32) {
        __shared__ float s_scale[NB1];    // 4 KiB
        for (int b = threadIdx.x; b < NB1; b += 256)
            s_scale[b] = __expf(ws_ms[b * 2] - M);
        __syncthreads();
        const int al = threadIdx.x >> 4;          // 0..15 -> dim within block
        const int ch = threadIdx.x & 15;          // 0..15 -> b-chunk
        const int a  = blockIdx.x * 16 + al;
        float acc = 0.f;
        for (int b = ch * (NB1 / 16); b < (ch + 1) * (NB1 / 16); ++b)
            acc += s_scale[b] * ws_c[(size_t)b * ATT + a];
        __shared__ float s_p[256];
        s_p[threadIdx.x] = acc;
        __syncthreads();
        if (ch == 0) {
            float v = 0.f;
            #pragma unroll
            for (int k = 0; k < 16; ++k) v += s_p[al * 16 + k];
            out[a] = v * IS;
        }
    }

    // Phase C: attention weights w[t] -> out[512+t)
    const int t = blockIdx.x * 256 + threadIdx.x;
    if (t < T) out[ATT + t] = __expf(ws_e[t] - M) * IS;
}

extern "C" void kernel_launch(void* const* d_in, const int* in_sizes, int n_in,
                              void* d_out, int out_size, void* d_ws, size_t ws_size,
                              hipStream_t stream)
{
    const float* dec_z    = (const float*)d_in[0];
    const float* att_prev = (const float*)d_in[1];
    const float* pre      = (const float*)d_in[2];
    const float* enc_h    = (const float*)d_in[3];
    const float* mask     = (const float*)d_in[4];
    const float* conv_w   = (const float*)d_in[5];
    const float* w_att    = (const float*)d_in[6];
    const float* w_dec    = (const float*)d_in[7];
    const float* w_gvec   = (const float*)d_in[8];
    const float* b_gvec   = (const float*)d_in[9];
    const int T = in_sizes[1];

    float* ws       = (float*)d_ws;
    float* ws_dec   = ws;                          // 512
    float* ws_aconv = ws_dec + ATT;                // T*PCH (16B-aligned)
    float* ws_e     = ws_aconv + (size_t)T * PCH;  // T
    float* ws_ms    = ws_e + T;                    // NB1*2
    float* ws_c     = ws_ms + NB1 * 2;             // NB1*512
    float* out      = (float*)d_out;

    const int nbconv = (T + CT - 1) / CT;
    const int nb2    = (T + 255) / 256;            // 196 >= 32 blocks for Phase B

    hipLaunchKernelGGL(k0_conv_dec, dim3(nbconv + ATT / 4), dim3(256), 0, stream,
                       att_prev, conv_w, dec_z, w_dec, ws_aconv, ws_dec, T, nbconv);
    hipLaunchKernelGGL(k1_scores, dim3(NB1), dim3(256), 0, stream,
                       pre, enc_h, mask, w_att, w_gvec, b_gvec, ws_dec, ws_aconv,
                       ws_e, ws_ms, ws_c, T);
    hipLaunchKernelGGL(k2_final, dim3(nb2), dim3(256), 0, stream,
                       ws_e, ws_ms, ws_c, out, T);
}